// Round 2
// baseline (135.636 us; speedup 1.0000x reference)
//
#include <hip/hip_runtime.h>

#define NV 65536       // total vectors (16*4096)
#define D 64           // embedding dim
#define K 1024         // codebook size
#define MBLK 128       // vectors per block
#define KTILE 64       // codes per LDS tile
#define PADX 132       // xT row stride (words)
#define PADE 68        // eT row stride (words)
#define LOSS_OFF 4194304
#define IDX_OFF  4194305

// Per-code squared norms, replicating numpy fp32 pairwise-8 summation exactly
// (squares rounded separately; 8 unrolled accumulators; fixed combine tree).
__global__ void vq_prep(const float* __restrict__ E, float* __restrict__ eSq,
                        float* __restrict__ loss) {
  int k = blockIdx.x * 256 + threadIdx.x;
  if (k == 0) *loss = 0.0f;
  if (k < K) {
    const float* row = E + (size_t)k * D;
    float r[8];
#pragma unroll
    for (int j = 0; j < 8; ++j) r[j] = __fmul_rn(row[j], row[j]);
#pragma unroll
    for (int i = 8; i < D; i += 8)
#pragma unroll
      for (int j = 0; j < 8; ++j)
        r[j] = __fadd_rn(r[j], __fmul_rn(row[i + j], row[i + j]));
    eSq[k] = __fadd_rn(
        __fadd_rn(__fadd_rn(r[0], r[1]), __fadd_rn(r[2], r[3])),
        __fadd_rn(__fadd_rn(r[4], r[5]), __fadd_rn(r[6], r[7])));
  }
}

__global__ __launch_bounds__(256, 3) void vq_main(
    const float* __restrict__ X, const float* __restrict__ E,
    const float* __restrict__ eSq, float* __restrict__ out) {
  __shared__ float xT[D * PADX];   // 33792 B, [d][v] transposed
  __shared__ float eT[D * PADE];   // 17408 B, [d][code] transposed
  __shared__ float sxx[MBLK];      // numpy-exact ||x||^2 per vector
  __shared__ int sidx[MBLK];

  const int t = threadIdx.x;
  const int bv0 = blockIdx.x * MBLK;

  // Stage X tile transposed (coalesced float4 reads).
#pragma unroll
  for (int i = 0; i < 8; ++i) {
    int c = t + 256 * i;
    int v = c >> 4, dc = c & 15;
    float4 xv = *reinterpret_cast<const float4*>(X + (size_t)(bv0 + v) * D + dc * 4);
    xT[(dc * 4 + 0) * PADX + v] = xv.x;
    xT[(dc * 4 + 1) * PADX + v] = xv.y;
    xT[(dc * 4 + 2) * PADX + v] = xv.z;
    xT[(dc * 4 + 3) * PADX + v] = xv.w;
  }
  __syncthreads();

  // ||x||^2 per vector, numpy pairwise-8 order, strict IEEE mul/add (no FMA).
  if (t < MBLK) {
    float r[8];
#pragma unroll
    for (int j = 0; j < 8; ++j) {
      float x0 = xT[j * PADX + t];
      r[j] = __fmul_rn(x0, x0);
    }
#pragma unroll
    for (int i = 8; i < D; i += 8)
#pragma unroll
      for (int j = 0; j < 8; ++j) {
        float xi = xT[(i + j) * PADX + t];
        r[j] = __fadd_rn(r[j], __fmul_rn(xi, xi));
      }
    sxx[t] = __fadd_rn(
        __fadd_rn(__fadd_rn(r[0], r[1]), __fadd_rn(r[2], r[3])),
        __fadd_rn(__fadd_rn(r[4], r[5]), __fadd_rn(r[6], r[7])));
  }
  __syncthreads();

  const int tx = t & 15;   // 16 code groups x 4 codes
  const int ty = t >> 4;   // 16 vector groups x 8 vectors
  const int v0 = ty * 8;

  float xxv[8];
#pragma unroll
  for (int j = 0; j < 8; ++j) xxv[j] = sxx[v0 + j];

  float best[8];
  int bidx[8];
#pragma unroll
  for (int j = 0; j < 8; ++j) { best[j] = 3.4e38f; bidx[j] = 0; }

  for (int tile = 0; tile < K / KTILE; ++tile) {
    if (tile) __syncthreads();  // previous tile's eT reads done
#pragma unroll
    for (int i = 0; i < 4; ++i) {
      int c2 = t + 256 * i;
      int code = c2 & 63, dc = c2 >> 6;
      float4 ev = *reinterpret_cast<const float4*>(
          E + (size_t)(tile * KTILE + code) * D + dc * 4);
      eT[(dc * 4 + 0) * PADE + code] = ev.x;
      eT[(dc * 4 + 1) * PADE + code] = ev.y;
      eT[(dc * 4 + 2) * PADE + code] = ev.z;
      eT[(dc * 4 + 3) * PADE + code] = ev.w;
    }
    float es[4];
#pragma unroll
    for (int cc = 0; cc < 4; ++cc) es[cc] = eSq[tile * KTILE + tx * 4 + cc];
    __syncthreads();

    float acc[4][8];
#pragma unroll
    for (int cc = 0; cc < 4; ++cc)
#pragma unroll
      for (int j = 0; j < 8; ++j) acc[cc][j] = 0.0f;

#pragma unroll 8
    for (int d = 0; d < D; ++d) {
      float4 e4 = *reinterpret_cast<const float4*>(&eT[d * PADE + tx * 4]);
      float4 xa = *reinterpret_cast<const float4*>(&xT[d * PADX + v0]);
      float4 xb = *reinterpret_cast<const float4*>(&xT[d * PADX + v0 + 4]);
      float ev[4] = {e4.x, e4.y, e4.z, e4.w};
      float xv[8] = {xa.x, xa.y, xa.z, xa.w, xb.x, xb.y, xb.z, xb.w};
#pragma unroll
      for (int cc = 0; cc < 4; ++cc)
#pragma unroll
        for (int j = 0; j < 8; ++j)
          acc[cc][j] = fmaf(ev[cc], xv[j], acc[cc][j]);
    }

    // Reference-exact fp32 distance: d = fl(fl(xx+ee) - 2*m); 2*m is exact.
    // Strict < over ascending code order = numpy first-occurrence argmin.
#pragma unroll
    for (int cc = 0; cc < 4; ++cc) {
      int code = tile * KTILE + tx * 4 + cc;
#pragma unroll
      for (int j = 0; j < 8; ++j) {
        float A = __fadd_rn(xxv[j], es[cc]);
        float dq = __fsub_rn(A, 2.0f * acc[cc][j]);
        if (dq < best[j]) { best[j] = dq; bidx[j] = code; }
      }
    }
  }

  // Lexicographic (val, idx) argmin across the 16 tx lanes.
#pragma unroll
  for (int j = 0; j < 8; ++j) {
    float bv = best[j];
    int bi = bidx[j];
#pragma unroll
    for (int off = 1; off < 16; off <<= 1) {
      float ov = __shfl_xor(bv, off, 64);
      int oi = __shfl_xor(bi, off, 64);
      if (ov < bv || (ov == bv && oi < bi)) { bv = ov; bi = oi; }
    }
    if (tx == 0) sidx[v0 + j] = bi;
  }
  __syncthreads();

  // Epilogue: gather codebook rows, write quantized, accumulate loss.
  float lsum = 0.0f;
#pragma unroll
  for (int i = 0; i < 8; ++i) {
    int c = t + 256 * i;
    int v = c >> 4, dc = c & 15;
    int code = sidx[v];
    float4 e4 = *reinterpret_cast<const float4*>(E + (size_t)code * D + dc * 4);
    float x0 = xT[(dc * 4 + 0) * PADX + v];
    float x1 = xT[(dc * 4 + 1) * PADX + v];
    float x2 = xT[(dc * 4 + 2) * PADX + v];
    float x3 = xT[(dc * 4 + 3) * PADX + v];
    float d0 = e4.x - x0, d1 = e4.y - x1, d2 = e4.z - x2, d3 = e4.w - x3;
    lsum += d0 * d0 + d1 * d1 + d2 * d2 + d3 * d3;
    *reinterpret_cast<float4*>(out + (size_t)(bv0 + v) * D + dc * 4) = e4;
  }
  if (t < MBLK) out[IDX_OFF + bv0 + t] = (float)sidx[t];

#pragma unroll
  for (int off = 1; off < 64; off <<= 1) lsum += __shfl_xor(lsum, off, 64);
  if ((t & 63) == 0)
    atomicAdd(out + LOSS_OFF, lsum * (1.25f / (float)((size_t)NV * D)));
}

extern "C" void kernel_launch(void* const* d_in, const int* in_sizes, int n_in,
                              void* d_out, int out_size, void* d_ws, size_t ws_size,
                              hipStream_t stream) {
  const float* X = (const float*)d_in[0];
  const float* E = (const float*)d_in[1];
  float* out = (float*)d_out;
  float* eSq = (float*)d_ws;  // 4 KB scratch
  vq_prep<<<4, 256, 0, stream>>>(E, eSq, out + LOSS_OFF);
  vq_main<<<NV / MBLK, 256, 0, stream>>>(X, E, eSq, out);
}